// Round 7
// baseline (3319.150 us; speedup 1.0000x reference)
//
#include <hip/hip_runtime.h>

#define TT 512
#define BB 1024
#define XD 24
#define ZD 16

typedef __attribute__((ext_vector_type(4))) _Float16 half4;
typedef __attribute__((ext_vector_type(4))) float f32x4;
typedef unsigned long long u64;

__device__ __forceinline__ f32x4 MFMA16(half4 a, half4 b, f32x4 c) {
#if defined(__HIP_DEVICE_COMPILE__)
    return __builtin_amdgcn_mfma_f32_16x16x16f16(a, b, c, 0, 0, 0);
#else
    return c;   // host pass only needs to parse
#endif
}

// Raw barrier: waits LDS ops only; global prefetch loads stay in flight (no vmcnt drain).
#define BAR() asm volatile("s_waitcnt lgkmcnt(0)\n\ts_barrier" ::: "memory")

__device__ __forceinline__ f32x4 Z4() { return (f32x4){0.f, 0.f, 0.f, 0.f}; }

__device__ __forceinline__ float sigm(float x) { return 1.0f / (1.0f + __expf(-x)); }

__device__ __forceinline__ float tanh_fast(float x) {
    return 1.0f - 2.0f / (1.0f + __expf(2.0f * x));   // saturates via inf/rcp
}

__device__ __forceinline__ float softplus_f(float x) {
    return fmaxf(x, 0.0f) + log1pf(__expf(-fabsf(x)));
}

// A-fragment of W^T (16 out-feats x 16 k). Lane l holds W[k0+(l>>4)*4+j][o0+(l&15)],
// zero-padded outside Kreal/Nreal. W row-major [K][N].
__device__ __forceinline__ half4 ldw(const float* W, int N, int Kreal, int Nreal,
                                     int k0, int o0, int lane) {
    int col = o0 + (lane & 15);
    int kb = k0 + ((lane >> 4) << 2);
    half4 r;
#pragma unroll
    for (int j = 0; j < 4; ++j) {
        int k = kb + j;
        float v = (k < Kreal && col < Nreal) ? W[(size_t)k * N + col] : 0.0f;
        r[j] = (_Float16)v;
    }
    return r;
}

__device__ __forceinline__ half4 cvt_relu(f32x4 a) {
    half4 r;
#pragma unroll
    for (int q = 0; q < 4; ++q) r[q] = (_Float16)fmaxf(a[q], 0.0f);
    return r;
}

__device__ __forceinline__ half4 cvt4(f32x4 a) {
    half4 r;
#pragma unroll
    for (int q = 0; q < 4; ++q) r[q] = (_Float16)a[q];
    return r;
}

__device__ __forceinline__ f32x4 ldb4(const float* b, int o, int lgr) {
    return *reinterpret_cast<const f32x4*>(b + o * 16 + lgr * 4);
}

__device__ __forceinline__ u64 h2u(half4 h) {
    union { half4 h; u64 u; } c; c.h = h; return c.u;
}
__device__ __forceinline__ half4 u2h(u64 u) {
    union { half4 h; u64 u; } c; c.u = u; return c.h;
}

__global__ __launch_bounds__(512, 2) void vrnn_kernel(
    const float* __restrict__ src, const float* __restrict__ eps,
    const float* __restrict__ Wx1, const float* __restrict__ bx1,
    const float* __restrict__ Wx2, const float* __restrict__ bx2,
    const float* __restrict__ Wz,  const float* __restrict__ bz,
    const float* __restrict__ We1, const float* __restrict__ be1,
    const float* __restrict__ We2, const float* __restrict__ be2,
    const float* __restrict__ Wem, const float* __restrict__ bem,
    const float* __restrict__ Wes, const float* __restrict__ bes,
    const float* __restrict__ Wih, const float* __restrict__ Whh,
    const float* __restrict__ Wf1, const float* __restrict__ bf1,
    const float* __restrict__ Wf2, const float* __restrict__ bf2,
    const float* __restrict__ Wf3, const float* __restrict__ bf3,
    float* __restrict__ out)
{
    // Activation exchange buffers per row-group, B-fragment form (8B/lane/frag)
    __shared__ u64 AXB[2][4 * 64];     // ax(t+1)
    __shared__ u64 A1B[2][4 * 64];     // a1(t)
    __shared__ u64 PZB[2][4 * 64];     // phi_z(t)
    __shared__ u64 HB[2][4 * 64];      // h
    __shared__ u64 PXB[2][2][4 * 64];  // [group][t&1] phi_x, double-buffered

    const int tid = threadIdx.x;
    const int wid = tid >> 6;
    const int ws = wid & 3;        // o-tile slice
    const int g = wid >> 2;        // row group (0/1)
    const int lane = tid & 63;
    const int lcol = lane & 15;    // batch column
    const int lgr = lane >> 4;
    const int r0 = blockIdx.x * 32 + g * 16;
    const int o0w = ws * 16;

    // ---------------- weights (registers, per-wave slices) ----------------
    half4 wx1f[2], wx2f[4], we1f[8], we2f[4][4], wemf[4], wesf[4], wzf;
    wx1f[0] = ldw(Wx1, 64, 24, 64, 0, o0w, lane);
    wx1f[1] = ldw(Wx1, 64, 24, 64, 16, o0w, lane);
#pragma unroll
    for (int kt = 0; kt < 4; ++kt) wx2f[kt] = ldw(Wx2, 64, 64, 64, kt * 16, o0w, lane);
#pragma unroll
    for (int kt = 0; kt < 8; ++kt) we1f[kt] = ldw(We1, 64, 128, 64, kt * 16, o0w, lane);
#pragma unroll
    for (int o = 0; o < 4; ++o)
#pragma unroll
        for (int kt = 0; kt < 4; ++kt) we2f[o][kt] = ldw(We2, 64, 64, 64, kt * 16, o * 16, lane);
#pragma unroll
    for (int kt = 0; kt < 4; ++kt) {
        wemf[kt] = ldw(Wem, 16, 64, 16, kt * 16, 0, lane);
        wesf[kt] = ldw(Wes, 16, 64, 16, kt * 16, 0, lane);
    }
    wzf = ldw(Wz, 64, 16, 64, 0, o0w, lane);
    half4 wihf[3][8], whhf[3][4];
#pragma unroll
    for (int gg = 0; gg < 3; ++gg) {
#pragma unroll
        for (int kt = 0; kt < 8; ++kt) wihf[gg][kt] = ldw(Wih, 192, 128, 192, kt * 16, gg * 64 + o0w, lane);
#pragma unroll
        for (int kt = 0; kt < 4; ++kt) whhf[gg][kt] = ldw(Whh, 192, 64, 192, kt * 16, gg * 64 + o0w, lane);
    }
    const f32x4 B1 = ldb4(bx1, ws, lgr), B2 = ldb4(bx2, ws, lgr);
    const f32x4 BE1 = ldb4(be1, ws, lgr), BZ = ldb4(bz, ws, lgr);
    f32x4 BE2[4];
#pragma unroll
    for (int o = 0; o < 4; ++o) BE2[o] = ldb4(be2, o, lgr);
    const f32x4 BM = ldb4(bem, 0, lgr), BS = ldb4(bes, 0, lgr);

    const float* xb_ = src + (size_t)(r0 + lcol) * TT * XD;
    const float* eb_ = eps + (size_t)(r0 + lcol) * TT * ZD;

    // ---------------- prologue: phi_x(0) -> PXB[g][0]; h = 0 ----------------
    f32x4 fx0 = *reinterpret_cast<const f32x4*>(xb_ + lgr * 4);
    f32x4 fx1 = Z4();
    if (lgr < 2) fx1 = *reinterpret_cast<const f32x4*>(xb_ + 16 + lgr * 4);
    {
        half4 x0 = cvt4(fx0), x1 = cvt4(fx1);
        f32x4 a = MFMA16(wx1f[1], x1, MFMA16(wx1f[0], x0, B1));
        AXB[g][ws * 64 + lane] = h2u(cvt_relu(a));
    }
    HB[g][ws * 64 + lane] = 0ull;
    f32x4 hD = Z4();
    BAR();
    {
        half4 axb[4];
#pragma unroll
        for (int kt = 0; kt < 4; ++kt) axb[kt] = u2h(AXB[g][kt * 64 + lane]);
        f32x4 a = B2;
#pragma unroll
        for (int kt = 0; kt < 4; ++kt) a = MFMA16(wx2f[kt], axb[kt], a);
        PXB[g][0][ws * 64 + lane] = h2u(cvt_relu(a));
    }
    // prefetch x(1), eps(0) — stay in flight across raw barriers
    fx0 = *reinterpret_cast<const f32x4*>(xb_ + XD + lgr * 4);
    fx1 = Z4();
    if (lgr < 2) fx1 = *reinterpret_cast<const f32x4*>(xb_ + XD + 16 + lgr * 4);
    f32x4 fe = *reinterpret_cast<const f32x4*>(eb_ + lgr * 4);
    BAR();

    f32x4 pzlast = Z4();
    half4 pxb[4], pzbL[4];

#pragma unroll 1
    for (int t = 0; t < TT; ++t) {
        // ================= P1: s3 + gh + s1(t+1) =================
        half4 hb[4];
#pragma unroll
        for (int kt = 0; kt < 4; ++kt) hb[kt] = u2h(HB[g][kt * 64 + lane]);
#pragma unroll
        for (int kt = 0; kt < 4; ++kt) pxb[kt] = u2h(PXB[g][t & 1][kt * 64 + lane]);

        {   // s3: a1 o-tile ws
            f32x4 a = BE1;
#pragma unroll
            for (int kt = 0; kt < 4; ++kt) a = MFMA16(we1f[kt], pxb[kt], a);
            f32x4 b = Z4();
#pragma unroll
            for (int kt = 0; kt < 4; ++kt) b = MFMA16(we1f[4 + kt], hb[kt], b);
            A1B[g][ws * 64 + lane] = h2u(cvt_relu(a + b));
        }
        f32x4 ga[3];
#pragma unroll
        for (int gg = 0; gg < 3; ++gg) {   // gh for r,u,n (col-slice ws)
            f32x4 a = MFMA16(whhf[gg][1], hb[1], MFMA16(whhf[gg][0], hb[0], Z4()));
            f32x4 b = MFMA16(whhf[gg][3], hb[3], MFMA16(whhf[gg][2], hb[2], Z4()));
            ga[gg] = a + b;
        }
        if (t + 1 < TT) {   // s1(t+1)
            half4 x0 = cvt4(fx0), x1 = cvt4(fx1);
            f32x4 s = MFMA16(wx1f[1], x1, MFMA16(wx1f[0], x0, B1));
            AXB[g][ws * 64 + lane] = h2u(cvt_relu(s));
            if (t + 2 < TT) {
                fx0 = *reinterpret_cast<const f32x4*>(xb_ + (size_t)(t + 2) * XD + lgr * 4);
                fx1 = Z4();
                if (lgr < 2) fx1 = *reinterpret_cast<const f32x4*>(xb_ + (size_t)(t + 2) * XD + 16 + lgr * 4);
            }
        }
        BAR();

        // ================= P2: s4(redundant) + s5 + z + s6 + s2(t+1) =================
        half4 a1b[4];
#pragma unroll
        for (int kt = 0; kt < 4; ++kt) a1b[kt] = u2h(A1B[g][kt * 64 + lane]);
        half4 enb[4];
#pragma unroll
        for (int o = 0; o < 4; ++o) {
            f32x4 p = MFMA16(we2f[o][1], a1b[1], MFMA16(we2f[o][0], a1b[0], BE2[o]));
            f32x4 q = MFMA16(we2f[o][3], a1b[3], MFMA16(we2f[o][2], a1b[2], Z4()));
            enb[o] = cvt_relu(p + q);
        }
        f32x4 am = MFMA16(wemf[1], enb[1], MFMA16(wemf[0], enb[0], BM));
        f32x4 am2 = MFMA16(wemf[3], enb[3], MFMA16(wemf[2], enb[2], Z4()));
        f32x4 as_ = MFMA16(wesf[1], enb[1], MFMA16(wesf[0], enb[0], BS));
        f32x4 as2 = MFMA16(wesf[3], enb[3], MFMA16(wesf[2], enb[2], Z4()));
        f32x4 eC = fe;
        if (t + 1 < TT) fe = *reinterpret_cast<const f32x4*>(eb_ + (size_t)(t + 1) * ZD + lgr * 4);
        f32x4 zD;
#pragma unroll
        for (int q = 0; q < 4; ++q)
            zD[q] = eC[q] * softplus_f(as_[q] + as2[q]) + (am[q] + am2[q]);
        half4 zb = cvt4(zD);
        {   // s6: phi_z o-tile ws
            f32x4 a = MFMA16(wzf, zb, BZ);
            if (t == TT - 1) {
#pragma unroll
                for (int q = 0; q < 4; ++q) pzlast[q] = fmaxf(a[q], 0.0f);
            }
            PZB[g][ws * 64 + lane] = h2u(cvt_relu(a));
        }
        if (t + 1 < TT) {   // s2(t+1)
            half4 axb[4];
#pragma unroll
            for (int kt = 0; kt < 4; ++kt) axb[kt] = u2h(AXB[g][kt * 64 + lane]);
            f32x4 s = B2;
#pragma unroll
            for (int kt = 0; kt < 4; ++kt) s = MFMA16(wx2f[kt], axb[kt], s);
            PXB[g][(t + 1) & 1][ws * 64 + lane] = h2u(cvt_relu(s));
        }
        BAR();

        // ================= P3: GRU gates + h update (col-slice ws local) =================
#pragma unroll
        for (int kt = 0; kt < 4; ++kt) pzbL[kt] = u2h(PZB[g][kt * 64 + lane]);
        f32x4 gi[3];
#pragma unroll
        for (int gg = 0; gg < 3; ++gg) {
            f32x4 p = (gg < 2) ? ga[gg] : Z4();
#pragma unroll
            for (int kt = 0; kt < 4; ++kt) p = MFMA16(wihf[gg][kt], pxb[kt], p);
            f32x4 q = Z4();
#pragma unroll
            for (int kt = 0; kt < 4; ++kt) q = MFMA16(wihf[gg][4 + kt], pzbL[kt], q);
            gi[gg] = p + q;
        }
#pragma unroll
        for (int q = 0; q < 4; ++q) {
            float rr = sigm(gi[0][q]);
            float uu = sigm(gi[1][q]);
            float nn = tanh_fast(gi[2][q] + rr * ga[2][q]);
            hD[q] = (1.0f - uu) * nn + uu * hD[q];
        }
        HB[g][ws * 64 + lane] = h2u(cvt4(hD));
        BAR();
    }

    // ---------------- outputs ----------------
    // phi_z(T-1) f32 slice per wave
    float* po = out + BB + (size_t)(r0 + lcol) * 64;
    *reinterpret_cast<f32x4*>(po + o0w + lgr * 4) = pzlast;

    // regressor head (o-slice-0 wave of each group, register-chained)
    if (ws == 0) {
        half4 wf1t[4][4], wf2t[2][4], wf3t[2];
#pragma unroll
        for (int o = 0; o < 4; ++o)
#pragma unroll
            for (int kt = 0; kt < 4; ++kt) wf1t[o][kt] = ldw(Wf1, 64, 64, 64, kt * 16, o * 16, lane);
#pragma unroll
        for (int o = 0; o < 2; ++o)
#pragma unroll
            for (int kt = 0; kt < 4; ++kt) wf2t[o][kt] = ldw(Wf2, 32, 64, 32, kt * 16, o * 16, lane);
        wf3t[0] = ldw(Wf3, 1, 32, 1, 0, 0, lane);
        wf3t[1] = ldw(Wf3, 1, 32, 1, 16, 0, lane);

        half4 o1b[4];
#pragma unroll
        for (int o = 0; o < 4; ++o) {
            f32x4 a = ldb4(bf1, o, lgr);
#pragma unroll
            for (int kt = 0; kt < 4; ++kt) a = MFMA16(wf1t[o][kt], pzbL[kt], a);
            o1b[o] = cvt_relu(a);
        }
        half4 o2b[2];
#pragma unroll
        for (int o = 0; o < 2; ++o) {
            f32x4 a = ldb4(bf2, o, lgr);
#pragma unroll
            for (int kt = 0; kt < 4; ++kt) a = MFMA16(wf2t[o][kt], o1b[kt], a);
            o2b[o] = cvt_relu(a);
        }
        float b3 = bf3[0];
        f32x4 p = (f32x4){b3, b3, b3, b3};
        p = MFMA16(wf3t[0], o2b[0], p);
        p = MFMA16(wf3t[1], o2b[1], p);
        if (lgr == 0) out[r0 + lcol] = p[0];
    }
}

extern "C" void kernel_launch(void* const* d_in, const int* in_sizes, int n_in,
                              void* d_out, int out_size, void* d_ws, size_t ws_size,
                              hipStream_t stream) {
    (void)in_sizes; (void)n_in; (void)d_ws; (void)ws_size; (void)out_size;
    const float* src = (const float*)d_in[0];
    const float* eps = (const float*)d_in[1];
    const float* Wx1 = (const float*)d_in[2];
    const float* bx1 = (const float*)d_in[3];
    const float* Wx2 = (const float*)d_in[4];
    const float* bx2 = (const float*)d_in[5];
    const float* Wz  = (const float*)d_in[6];
    const float* bz  = (const float*)d_in[7];
    const float* We1 = (const float*)d_in[8];
    const float* be1 = (const float*)d_in[9];
    const float* We2 = (const float*)d_in[10];
    const float* be2 = (const float*)d_in[11];
    const float* Wem = (const float*)d_in[12];
    const float* bem = (const float*)d_in[13];
    const float* Wes = (const float*)d_in[14];
    const float* bes = (const float*)d_in[15];
    const float* Wih = (const float*)d_in[16];
    const float* Whh = (const float*)d_in[17];
    const float* Wf1 = (const float*)d_in[18];
    const float* bf1 = (const float*)d_in[19];
    const float* Wf2 = (const float*)d_in[20];
    const float* bf2 = (const float*)d_in[21];
    const float* Wf3 = (const float*)d_in[22];
    const float* bf3 = (const float*)d_in[23];
    float* out = (float*)d_out;

    hipLaunchKernelGGL(vrnn_kernel, dim3(BB / 32), dim3(512), 0, stream,
                       src, eps, Wx1, bx1, Wx2, bx2, Wz, bz, We1, be1, We2, be2,
                       Wem, bem, Wes, bes, Wih, Whh, Wf1, bf1, Wf2, bf2, Wf3, bf3, out);
}

// Round 8
// 3318.985 us; speedup vs baseline: 1.0000x; 1.0000x over previous
//
#include <hip/hip_runtime.h>

#define TT 512
#define BB 1024
#define XD 24
#define ZD 16

typedef __attribute__((ext_vector_type(4))) _Float16 half4;
typedef __attribute__((ext_vector_type(4))) float f32x4;
typedef unsigned long long u64;

__device__ __forceinline__ f32x4 MFMA16(half4 a, half4 b, f32x4 c) {
#if defined(__HIP_DEVICE_COMPILE__)
    return __builtin_amdgcn_mfma_f32_16x16x16f16(a, b, c, 0, 0, 0);
#else
    return c;   // host pass only needs to parse
#endif
}

// Raw barrier: waits LDS ops only; global prefetch loads stay in flight (no vmcnt drain).
#define BAR() asm volatile("s_waitcnt lgkmcnt(0)\n\ts_barrier" ::: "memory")

__device__ __forceinline__ f32x4 Z4() { return (f32x4){0.f, 0.f, 0.f, 0.f}; }

__device__ __forceinline__ float sigm(float x) { return 1.0f / (1.0f + __expf(-x)); }

__device__ __forceinline__ float tanh_fast(float x) {
    return 1.0f - 2.0f / (1.0f + __expf(2.0f * x));   // saturates via inf/rcp
}

__device__ __forceinline__ float softplus_f(float x) {
    return fmaxf(x, 0.0f) + log1pf(__expf(-fabsf(x)));
}

// A-fragment of W^T (16 out-feats x 16 k). Lane l holds W[k0+(l>>4)*4+j][o0+(l&15)],
// zero-padded outside Kreal/Nreal. W row-major [K][N].
__device__ __forceinline__ half4 ldw(const float* W, int N, int Kreal, int Nreal,
                                     int k0, int o0, int lane) {
    int col = o0 + (lane & 15);
    int kb = k0 + ((lane >> 4) << 2);
    half4 r;
#pragma unroll
    for (int j = 0; j < 4; ++j) {
        int k = kb + j;
        float v = (k < Kreal && col < Nreal) ? W[(size_t)k * N + col] : 0.0f;
        r[j] = (_Float16)v;
    }
    return r;
}

__device__ __forceinline__ half4 cvt_relu(f32x4 a) {
    half4 r;
#pragma unroll
    for (int q = 0; q < 4; ++q) r[q] = (_Float16)fmaxf(a[q], 0.0f);
    return r;
}

__device__ __forceinline__ half4 cvt4(f32x4 a) {
    half4 r;
#pragma unroll
    for (int q = 0; q < 4; ++q) r[q] = (_Float16)a[q];
    return r;
}

__device__ __forceinline__ f32x4 ldb4(const float* b, int o, int lgr) {
    return *reinterpret_cast<const f32x4*>(b + o * 16 + lgr * 4);
}

__device__ __forceinline__ u64 h2u(half4 h) {
    union { half4 h; u64 u; } c; c.h = h; return c.u;
}
__device__ __forceinline__ half4 u2h(u64 u) {
    union { half4 h; u64 u; } c; c.u = u; return c.h;
}

__global__ __launch_bounds__(512, 1) void vrnn_kernel(
    const float* __restrict__ src, const float* __restrict__ eps,
    const float* __restrict__ Wx1, const float* __restrict__ bx1,
    const float* __restrict__ Wx2, const float* __restrict__ bx2,
    const float* __restrict__ Wz,  const float* __restrict__ bz,
    const float* __restrict__ We1, const float* __restrict__ be1,
    const float* __restrict__ We2, const float* __restrict__ be2,
    const float* __restrict__ Wem, const float* __restrict__ bem,
    const float* __restrict__ Wes, const float* __restrict__ bes,
    const float* __restrict__ Wih, const float* __restrict__ Whh,
    const float* __restrict__ Wf1, const float* __restrict__ bf1,
    const float* __restrict__ Wf2, const float* __restrict__ bf2,
    const float* __restrict__ Wf3, const float* __restrict__ bf3,
    float* __restrict__ out)
{
    // Activation exchange buffers per row-group, B-fragment form (8B/lane/frag)
    __shared__ u64 AXB[2][4 * 64];     // ax(t+1)
    __shared__ u64 A1B[2][4 * 64];     // a1(t)
    __shared__ u64 PZB[2][4 * 64];     // phi_z(t)
    __shared__ u64 HB[2][4 * 64];      // h
    __shared__ u64 PXB[2][2][4 * 64];  // [group][t&1] phi_x, double-buffered

    const int tid = threadIdx.x;
    const int wid = tid >> 6;
    const int ws = wid & 3;        // o-tile slice
    const int g = wid >> 2;        // row group (0/1)
    const int lane = tid & 63;
    const int lcol = lane & 15;    // batch column
    const int lgr = lane >> 4;
    const int r0 = blockIdx.x * 32 + g * 16;
    const int o0w = ws * 16;

    // ---------------- weights (registers, per-wave slices) ----------------
    half4 wx1f[2], wx2f[4], we1f[8], we2f[4][4], wemf[4], wesf[4], wzf;
    wx1f[0] = ldw(Wx1, 64, 24, 64, 0, o0w, lane);
    wx1f[1] = ldw(Wx1, 64, 24, 64, 16, o0w, lane);
#pragma unroll
    for (int kt = 0; kt < 4; ++kt) wx2f[kt] = ldw(Wx2, 64, 64, 64, kt * 16, o0w, lane);
#pragma unroll
    for (int kt = 0; kt < 8; ++kt) we1f[kt] = ldw(We1, 64, 128, 64, kt * 16, o0w, lane);
#pragma unroll
    for (int o = 0; o < 4; ++o)
#pragma unroll
        for (int kt = 0; kt < 4; ++kt) we2f[o][kt] = ldw(We2, 64, 64, 64, kt * 16, o * 16, lane);
#pragma unroll
    for (int kt = 0; kt < 4; ++kt) {
        wemf[kt] = ldw(Wem, 16, 64, 16, kt * 16, 0, lane);
        wesf[kt] = ldw(Wes, 16, 64, 16, kt * 16, 0, lane);
    }
    wzf = ldw(Wz, 64, 16, 64, 0, o0w, lane);
    half4 wihf[3][8], whhf[3][4];
#pragma unroll
    for (int gg = 0; gg < 3; ++gg) {
#pragma unroll
        for (int kt = 0; kt < 8; ++kt) wihf[gg][kt] = ldw(Wih, 192, 128, 192, kt * 16, gg * 64 + o0w, lane);
#pragma unroll
        for (int kt = 0; kt < 4; ++kt) whhf[gg][kt] = ldw(Whh, 192, 64, 192, kt * 16, gg * 64 + o0w, lane);
    }
    const f32x4 B1 = ldb4(bx1, ws, lgr), B2 = ldb4(bx2, ws, lgr);
    const f32x4 BE1 = ldb4(be1, ws, lgr), BZ = ldb4(bz, ws, lgr);
    f32x4 BE2[4];
#pragma unroll
    for (int o = 0; o < 4; ++o) BE2[o] = ldb4(be2, o, lgr);
    const f32x4 BM = ldb4(bem, 0, lgr), BS = ldb4(bes, 0, lgr);

    const float* xb_ = src + (size_t)(r0 + lcol) * TT * XD;
    const float* eb_ = eps + (size_t)(r0 + lcol) * TT * ZD;

    // ---------------- prologue: phi_x(0) -> PXB[g][0]; h = 0 ----------------
    f32x4 fx0 = *reinterpret_cast<const f32x4*>(xb_ + lgr * 4);
    f32x4 fx1 = Z4();
    if (lgr < 2) fx1 = *reinterpret_cast<const f32x4*>(xb_ + 16 + lgr * 4);
    {
        half4 x0 = cvt4(fx0), x1 = cvt4(fx1);
        f32x4 a = MFMA16(wx1f[1], x1, MFMA16(wx1f[0], x0, B1));
        AXB[g][ws * 64 + lane] = h2u(cvt_relu(a));
    }
    HB[g][ws * 64 + lane] = 0ull;
    f32x4 hD = Z4();
    BAR();
    {
        half4 axb[4];
#pragma unroll
        for (int kt = 0; kt < 4; ++kt) axb[kt] = u2h(AXB[g][kt * 64 + lane]);
        f32x4 a = B2;
#pragma unroll
        for (int kt = 0; kt < 4; ++kt) a = MFMA16(wx2f[kt], axb[kt], a);
        PXB[g][0][ws * 64 + lane] = h2u(cvt_relu(a));
    }
    // prefetch x(1), eps(0) — stay in flight across raw barriers
    fx0 = *reinterpret_cast<const f32x4*>(xb_ + XD + lgr * 4);
    fx1 = Z4();
    if (lgr < 2) fx1 = *reinterpret_cast<const f32x4*>(xb_ + XD + 16 + lgr * 4);
    f32x4 fe = *reinterpret_cast<const f32x4*>(eb_ + lgr * 4);
    BAR();

    f32x4 pzlast = Z4();
    half4 pxb[4], pzbL[4];

#pragma unroll 1
    for (int t = 0; t < TT; ++t) {
        // ================= P1: s3 + gh + s1(t+1) =================
        half4 hb[4];
#pragma unroll
        for (int kt = 0; kt < 4; ++kt) hb[kt] = u2h(HB[g][kt * 64 + lane]);
#pragma unroll
        for (int kt = 0; kt < 4; ++kt) pxb[kt] = u2h(PXB[g][t & 1][kt * 64 + lane]);

        {   // s3: a1 o-tile ws
            f32x4 a = BE1;
#pragma unroll
            for (int kt = 0; kt < 4; ++kt) a = MFMA16(we1f[kt], pxb[kt], a);
            f32x4 b = Z4();
#pragma unroll
            for (int kt = 0; kt < 4; ++kt) b = MFMA16(we1f[4 + kt], hb[kt], b);
            A1B[g][ws * 64 + lane] = h2u(cvt_relu(a + b));
        }
        f32x4 ga[3];
#pragma unroll
        for (int gg = 0; gg < 3; ++gg) {   // gh for r,u,n (col-slice ws)
            f32x4 a = MFMA16(whhf[gg][1], hb[1], MFMA16(whhf[gg][0], hb[0], Z4()));
            f32x4 b = MFMA16(whhf[gg][3], hb[3], MFMA16(whhf[gg][2], hb[2], Z4()));
            ga[gg] = a + b;
        }
        if (t + 1 < TT) {   // s1(t+1)
            half4 x0 = cvt4(fx0), x1 = cvt4(fx1);
            f32x4 s = MFMA16(wx1f[1], x1, MFMA16(wx1f[0], x0, B1));
            AXB[g][ws * 64 + lane] = h2u(cvt_relu(s));
            if (t + 2 < TT) {
                fx0 = *reinterpret_cast<const f32x4*>(xb_ + (size_t)(t + 2) * XD + lgr * 4);
                fx1 = Z4();
                if (lgr < 2) fx1 = *reinterpret_cast<const f32x4*>(xb_ + (size_t)(t + 2) * XD + 16 + lgr * 4);
            }
        }
        BAR();

        // ================= P2: s4(redundant) + s5 + z + s6 + s2(t+1) =================
        half4 a1b[4];
#pragma unroll
        for (int kt = 0; kt < 4; ++kt) a1b[kt] = u2h(A1B[g][kt * 64 + lane]);
        half4 enb[4];
#pragma unroll
        for (int o = 0; o < 4; ++o) {
            f32x4 p = MFMA16(we2f[o][1], a1b[1], MFMA16(we2f[o][0], a1b[0], BE2[o]));
            f32x4 q = MFMA16(we2f[o][3], a1b[3], MFMA16(we2f[o][2], a1b[2], Z4()));
            enb[o] = cvt_relu(p + q);
        }
        f32x4 am = MFMA16(wemf[1], enb[1], MFMA16(wemf[0], enb[0], BM));
        f32x4 am2 = MFMA16(wemf[3], enb[3], MFMA16(wemf[2], enb[2], Z4()));
        f32x4 as_ = MFMA16(wesf[1], enb[1], MFMA16(wesf[0], enb[0], BS));
        f32x4 as2 = MFMA16(wesf[3], enb[3], MFMA16(wesf[2], enb[2], Z4()));
        f32x4 eC = fe;
        if (t + 1 < TT) fe = *reinterpret_cast<const f32x4*>(eb_ + (size_t)(t + 1) * ZD + lgr * 4);
        f32x4 zD;
#pragma unroll
        for (int q = 0; q < 4; ++q)
            zD[q] = eC[q] * softplus_f(as_[q] + as2[q]) + (am[q] + am2[q]);
        half4 zb = cvt4(zD);
        {   // s6: phi_z o-tile ws
            f32x4 a = MFMA16(wzf, zb, BZ);
            if (t == TT - 1) {
#pragma unroll
                for (int q = 0; q < 4; ++q) pzlast[q] = fmaxf(a[q], 0.0f);
            }
            PZB[g][ws * 64 + lane] = h2u(cvt_relu(a));
        }
        if (t + 1 < TT) {   // s2(t+1)
            half4 axb[4];
#pragma unroll
            for (int kt = 0; kt < 4; ++kt) axb[kt] = u2h(AXB[g][kt * 64 + lane]);
            f32x4 s = B2;
#pragma unroll
            for (int kt = 0; kt < 4; ++kt) s = MFMA16(wx2f[kt], axb[kt], s);
            PXB[g][(t + 1) & 1][ws * 64 + lane] = h2u(cvt_relu(s));
        }
        BAR();

        // ================= P3: GRU gates + h update (col-slice ws local) =================
#pragma unroll
        for (int kt = 0; kt < 4; ++kt) pzbL[kt] = u2h(PZB[g][kt * 64 + lane]);
        f32x4 gi[3];
#pragma unroll
        for (int gg = 0; gg < 3; ++gg) {
            f32x4 p = (gg < 2) ? ga[gg] : Z4();
#pragma unroll
            for (int kt = 0; kt < 4; ++kt) p = MFMA16(wihf[gg][kt], pxb[kt], p);
            f32x4 q = Z4();
#pragma unroll
            for (int kt = 0; kt < 4; ++kt) q = MFMA16(wihf[gg][4 + kt], pzbL[kt], q);
            gi[gg] = p + q;
        }
#pragma unroll
        for (int q = 0; q < 4; ++q) {
            float rr = sigm(gi[0][q]);
            float uu = sigm(gi[1][q]);
            float nn = tanh_fast(gi[2][q] + rr * ga[2][q]);
            hD[q] = (1.0f - uu) * nn + uu * hD[q];
        }
        HB[g][ws * 64 + lane] = h2u(cvt4(hD));
        BAR();
    }

    // ---------------- outputs ----------------
    // phi_z(T-1) f32 slice per wave
    float* po = out + BB + (size_t)(r0 + lcol) * 64;
    *reinterpret_cast<f32x4*>(po + o0w + lgr * 4) = pzlast;

    // regressor head (o-slice-0 wave of each group, register-chained)
    if (ws == 0) {
        half4 wf1t[4][4], wf2t[2][4], wf3t[2];
#pragma unroll
        for (int o = 0; o < 4; ++o)
#pragma unroll
            for (int kt = 0; kt < 4; ++kt) wf1t[o][kt] = ldw(Wf1, 64, 64, 64, kt * 16, o * 16, lane);
#pragma unroll
        for (int o = 0; o < 2; ++o)
#pragma unroll
            for (int kt = 0; kt < 4; ++kt) wf2t[o][kt] = ldw(Wf2, 32, 64, 32, kt * 16, o * 16, lane);
        wf3t[0] = ldw(Wf3, 1, 32, 1, 0, 0, lane);
        wf3t[1] = ldw(Wf3, 1, 32, 1, 16, 0, lane);

        half4 o1b[4];
#pragma unroll
        for (int o = 0; o < 4; ++o) {
            f32x4 a = ldb4(bf1, o, lgr);
#pragma unroll
            for (int kt = 0; kt < 4; ++kt) a = MFMA16(wf1t[o][kt], pzbL[kt], a);
            o1b[o] = cvt_relu(a);
        }
        half4 o2b[2];
#pragma unroll
        for (int o = 0; o < 2; ++o) {
            f32x4 a = ldb4(bf2, o, lgr);
#pragma unroll
            for (int kt = 0; kt < 4; ++kt) a = MFMA16(wf2t[o][kt], o1b[kt], a);
            o2b[o] = cvt_relu(a);
        }
        float b3 = bf3[0];
        f32x4 p = (f32x4){b3, b3, b3, b3};
        p = MFMA16(wf3t[0], o2b[0], p);
        p = MFMA16(wf3t[1], o2b[1], p);
        if (lgr == 0) out[r0 + lcol] = p[0];
    }
}

extern "C" void kernel_launch(void* const* d_in, const int* in_sizes, int n_in,
                              void* d_out, int out_size, void* d_ws, size_t ws_size,
                              hipStream_t stream) {
    (void)in_sizes; (void)n_in; (void)d_ws; (void)ws_size; (void)out_size;
    const float* src = (const float*)d_in[0];
    const float* eps = (const float*)d_in[1];
    const float* Wx1 = (const float*)d_in[2];
    const float* bx1 = (const float*)d_in[3];
    const float* Wx2 = (const float*)d_in[4];
    const float* bx2 = (const float*)d_in[5];
    const float* Wz  = (const float*)d_in[6];
    const float* bz  = (const float*)d_in[7];
    const float* We1 = (const float*)d_in[8];
    const float* be1 = (const float*)d_in[9];
    const float* We2 = (const float*)d_in[10];
    const float* be2 = (const float*)d_in[11];
    const float* Wem = (const float*)d_in[12];
    const float* bem = (const float*)d_in[13];
    const float* Wes = (const float*)d_in[14];
    const float* bes = (const float*)d_in[15];
    const float* Wih = (const float*)d_in[16];
    const float* Whh = (const float*)d_in[17];
    const float* Wf1 = (const float*)d_in[18];
    const float* bf1 = (const float*)d_in[19];
    const float* Wf2 = (const float*)d_in[20];
    const float* bf2 = (const float*)d_in[21];
    const float* Wf3 = (const float*)d_in[22];
    const float* bf3 = (const float*)d_in[23];
    float* out = (float*)d_out;

    hipLaunchKernelGGL(vrnn_kernel, dim3(BB / 32), dim3(512), 0, stream,
                       src, eps, Wx1, bx1, Wx2, bx2, Wz, bz, We1, be1, We2, be2,
                       Wem, bem, Wes, bes, Wih, Whh, Wf1, bf1, Wf2, bf2, Wf3, bf3, out);
}

// Round 10
// 1345.241 us; speedup vs baseline: 2.4673x; 2.4672x over previous
//
#include <hip/hip_runtime.h>

#define TT 512
#define BB 1024
#define XD 24
#define ZD 16

typedef __attribute__((ext_vector_type(2))) _Float16 h2t;
typedef __attribute__((ext_vector_type(4))) _Float16 half4;
typedef __attribute__((ext_vector_type(8))) _Float16 half8;
typedef __attribute__((ext_vector_type(4))) float f32x4;
typedef unsigned long long u64;

__device__ __forceinline__ f32x4 MFMA16(half4 a, half4 b, f32x4 c) {
#if defined(__HIP_DEVICE_COMPILE__)
    return __builtin_amdgcn_mfma_f32_16x16x16f16(a, b, c, 0, 0, 0);
#else
    return c;
#endif
}
__device__ __forceinline__ f32x4 MFMA32(half8 a, half8 b, f32x4 c) {
#if defined(__HIP_DEVICE_COMPILE__)
    return __builtin_amdgcn_mfma_f32_16x16x32_f16(a, b, c, 0, 0, 0);
#else
    return c;
#endif
}
__device__ __forceinline__ h2t pkrtz(float a, float b) {
#if defined(__HIP_DEVICE_COMPILE__)
    union { __attribute__((ext_vector_type(2))) __fp16 f; h2t h; } c;
    c.f = __builtin_amdgcn_cvt_pkrtz(a, b);
    return c.h;
#else
    h2t r; r[0] = (_Float16)a; r[1] = (_Float16)b; return r;
#endif
}

// Raw barrier: waits LDS ops only; global prefetch loads stay in flight.
#define BAR() asm volatile("s_waitcnt lgkmcnt(0)\n\ts_barrier" ::: "memory")

__device__ __forceinline__ f32x4 Z4() { return (f32x4){0.f, 0.f, 0.f, 0.f}; }
__device__ __forceinline__ float sigm(float x) { return 1.0f / (1.0f + __expf(-x)); }
__device__ __forceinline__ float tanh_fast(float x) {
    return 1.0f - 2.0f / (1.0f + __expf(2.0f * x));
}
__device__ __forceinline__ float softplus_f(float x) {
    return fmaxf(x, 0.0f) + log1pf(__expf(-fabsf(x)));
}

// ---- packing helpers --------------------------------------------------------
__device__ __forceinline__ u64 packDr(f32x4 a) {   // relu + RTZ pack
    union { h2t p[2]; u64 u; } c;
    c.p[0] = pkrtz(fmaxf(a[0], 0.f), fmaxf(a[1], 0.f));
    c.p[1] = pkrtz(fmaxf(a[2], 0.f), fmaxf(a[3], 0.f));
    return c.u;
}
__device__ __forceinline__ u64 packD(f32x4 a) {    // RTZ pack (no relu)
    union { h2t p[2]; u64 u; } c;
    c.p[0] = pkrtz(a[0], a[1]);
    c.p[1] = pkrtz(a[2], a[3]);
    return c.u;
}
__device__ __forceinline__ u64 packD_rne(f32x4 a) { // RNE pack (recurrent h)
    union { _Float16 h[4]; u64 u; } c;
#pragma unroll
    for (int q = 0; q < 4; ++q) c.h[q] = (_Float16)a[q];
    return c.u;
}
__device__ __forceinline__ half4 u2h4(u64 u) {
    union { half4 h; u64 u; } c; c.u = u; return c.h;
}
__device__ __forceinline__ half8 mk8(u64 a, u64 b) {
    union { struct { u64 a, b; } s; half8 h; } c; c.s.a = a; c.s.b = b; return c.h;
}
__device__ __forceinline__ half8 xfrag(f32x4 A, f32x4 B) {
    union { h2t p[4]; half8 h; } c;
    c.p[0] = pkrtz(A[0], A[1]); c.p[1] = pkrtz(A[2], A[3]);
    c.p[2] = pkrtz(B[0], B[1]); c.p[3] = pkrtz(B[2], B[3]);
    return c.h;
}

// LDS word index for feature-group g (4 feats), batch col c
__device__ __forceinline__ int wofs(int g, int c) { return g * 16 + c; }

// ---- weight fragment loaders ------------------------------------------------
// x16 A-frag of W^T: lane holds W[k0+(l>>4)*4+j][o0+(l&15)], j=0..3
__device__ __forceinline__ half4 ldw(const float* W, int N, int Kreal, int Nreal,
                                     int k0, int o0, int lane) {
    int col = o0 + (lane & 15);
    int kb = k0 + ((lane >> 4) << 2);
    half4 r;
#pragma unroll
    for (int j = 0; j < 4; ++j) {
        int k = kb + j;
        float v = (k < Kreal && col < Nreal) ? W[(size_t)k * N + col] : 0.0f;
        r[j] = (_Float16)v;
    }
    return r;
}
// x32 A-frag of W^T: lane holds W[k0+(l>>4)*8+j][o0+(l&15)], j=0..7
__device__ __forceinline__ half8 ldw32(const float* W, int N, int Kreal, int Nreal,
                                       int k0, int o0, int lane) {
    int col = o0 + (lane & 15);
    int kb = k0 + ((lane >> 4) << 3);
    half8 r;
#pragma unroll
    for (int j = 0; j < 8; ++j) {
        int k = kb + j;
        float v = (k < Kreal && col < Nreal) ? W[(size_t)k * N + col] : 0.0f;
        r[j] = (_Float16)v;
    }
    return r;
}
__device__ __forceinline__ f32x4 ldb4(const float* b, int o, int lgr) {
    return *reinterpret_cast<const f32x4*>(b + o * 16 + lgr * 4);
}

__global__ __launch_bounds__(256, 1) void vrnn_kernel(
    const float* __restrict__ src, const float* __restrict__ eps,
    const float* __restrict__ Wx1, const float* __restrict__ bx1,
    const float* __restrict__ Wx2, const float* __restrict__ bx2,
    const float* __restrict__ Wz,  const float* __restrict__ bz,
    const float* __restrict__ We1, const float* __restrict__ be1,
    const float* __restrict__ We2, const float* __restrict__ be2,
    const float* __restrict__ Wem, const float* __restrict__ bem,
    const float* __restrict__ Wes, const float* __restrict__ bes,
    const float* __restrict__ Wih, const float* __restrict__ Whh,
    const float* __restrict__ Wf1, const float* __restrict__ bf1,
    const float* __restrict__ Wf2, const float* __restrict__ bf2,
    const float* __restrict__ Wf3, const float* __restrict__ bf3,
    float* __restrict__ out)
{
    // Each matrix: 16 k-groups x 16 cols of packed 4xf16 words
    __shared__ u64 AXW[256];
    __shared__ u64 A1W[256];
    __shared__ u64 PZW[256];
    __shared__ u64 HW[256];
    __shared__ u64 PXW[2][256];

    const int tid = threadIdx.x;
    const int ws = tid >> 6;       // wave = o-tile slice
    const int lane = tid & 63;
    const int lcol = lane & 15;    // batch col
    const int lgr = lane >> 4;
    const int r0 = blockIdx.x * 16;
    const int o0w = ws * 16;

    // ---------------- weights ----------------
    half8 wx1f = ldw32(Wx1, 64, 24, 64, 0, o0w, lane);
    half8 wx2f[2], we1f[4], we2f[4][2];
#pragma unroll
    for (int kt = 0; kt < 2; ++kt) wx2f[kt] = ldw32(Wx2, 64, 64, 64, kt * 32, o0w, lane);
#pragma unroll
    for (int kt = 0; kt < 4; ++kt) we1f[kt] = ldw32(We1, 64, 128, 64, kt * 32, o0w, lane);
#pragma unroll
    for (int o = 0; o < 4; ++o)
#pragma unroll
        for (int kt = 0; kt < 2; ++kt) we2f[o][kt] = ldw32(We2, 64, 64, 64, kt * 32, o * 16, lane);
    half4 wemf[4], wesf[4], wzf;
#pragma unroll
    for (int kt = 0; kt < 4; ++kt) {
        wemf[kt] = ldw(Wem, 16, 64, 16, kt * 16, 0, lane);
        wesf[kt] = ldw(Wes, 16, 64, 16, kt * 16, 0, lane);
    }
    wzf = ldw(Wz, 64, 16, 64, 0, o0w, lane);
    half8 wihf[3][4], whhf[3][2];
#pragma unroll
    for (int g = 0; g < 3; ++g) {
#pragma unroll
        for (int kt = 0; kt < 4; ++kt) wihf[g][kt] = ldw32(Wih, 192, 128, 192, kt * 32, g * 64 + o0w, lane);
#pragma unroll
        for (int kt = 0; kt < 2; ++kt) whhf[g][kt] = ldw32(Whh, 192, 64, 192, kt * 32, g * 64 + o0w, lane);
    }
    const f32x4 B1 = ldb4(bx1, ws, lgr), B2 = ldb4(bx2, ws, lgr);
    const f32x4 BE1 = ldb4(be1, ws, lgr), BZ = ldb4(bz, ws, lgr);
    f32x4 BE2[4];
#pragma unroll
    for (int o = 0; o < 4; ++o) BE2[o] = ldb4(be2, o, lgr);
    const f32x4 BM = ldb4(bem, 0, lgr), BS = ldb4(bes, 0, lgr);

    const float* xb_ = src + (size_t)(r0 + lcol) * TT * XD;
    const float* eb_ = eps + (size_t)(r0 + lcol) * TT * ZD;

    // ---------------- prologue ----------------
    f32x4 fxA = Z4(), fxB = Z4();
    if (lgr < 3) {
        fxA = *reinterpret_cast<const f32x4*>(xb_ + lgr * 8);
        fxB = *reinterpret_cast<const f32x4*>(xb_ + lgr * 8 + 4);
    }
    {
        f32x4 s = MFMA32(wx1f, xfrag(fxA, fxB), B1);
        AXW[wofs(ws * 4 + lgr, lcol)] = packDr(s);
    }
    HW[tid] = 0ull;
    f32x4 hD = Z4();
    BAR();
    {
        half8 ax0 = mk8(AXW[wofs(2 * lgr, lcol)], AXW[wofs(2 * lgr + 1, lcol)]);
        half8 ax1 = mk8(AXW[wofs(8 + 2 * lgr, lcol)], AXW[wofs(9 + 2 * lgr, lcol)]);
        f32x4 s = MFMA32(wx2f[1], ax1, MFMA32(wx2f[0], ax0, B2));
        PXW[0][wofs(ws * 4 + lgr, lcol)] = packDr(s);
    }
    fxA = Z4(); fxB = Z4();
    if (lgr < 3) {
        fxA = *reinterpret_cast<const f32x4*>(xb_ + XD + lgr * 8);
        fxB = *reinterpret_cast<const f32x4*>(xb_ + XD + lgr * 8 + 4);
    }
    f32x4 fe = *reinterpret_cast<const f32x4*>(eb_ + lgr * 4);
    BAR();

    f32x4 pzlast = Z4();
    half8 pxb0, pxb1;

#pragma unroll 1
    for (int t = 0; t < TT; ++t) {
        // ================= P1: s3 + gh + s1(t+1) =================
        half8 hb0 = mk8(HW[wofs(2 * lgr, lcol)], HW[wofs(2 * lgr + 1, lcol)]);
        half8 hb1 = mk8(HW[wofs(8 + 2 * lgr, lcol)], HW[wofs(9 + 2 * lgr, lcol)]);
        pxb0 = mk8(PXW[t & 1][wofs(2 * lgr, lcol)], PXW[t & 1][wofs(2 * lgr + 1, lcol)]);
        pxb1 = mk8(PXW[t & 1][wofs(8 + 2 * lgr, lcol)], PXW[t & 1][wofs(9 + 2 * lgr, lcol)]);

        {   // s3: a1 o-tile ws
            f32x4 a = MFMA32(we1f[1], pxb1, MFMA32(we1f[0], pxb0, BE1));
            f32x4 b = MFMA32(we1f[3], hb1, MFMA32(we1f[2], hb0, Z4()));
            A1W[wofs(ws * 4 + lgr, lcol)] = packDr(a + b);
        }
        f32x4 ga[3];
#pragma unroll
        for (int g = 0; g < 3; ++g)
            ga[g] = MFMA32(whhf[g][1], hb1, MFMA32(whhf[g][0], hb0, Z4()));
        if (t + 1 < TT) {   // s1(t+1)
            f32x4 s = MFMA32(wx1f, xfrag(fxA, fxB), B1);
            AXW[wofs(ws * 4 + lgr, lcol)] = packDr(s);
            if (t + 2 < TT) {
                fxA = Z4(); fxB = Z4();
                if (lgr < 3) {
                    fxA = *reinterpret_cast<const f32x4*>(xb_ + (size_t)(t + 2) * XD + lgr * 8);
                    fxB = *reinterpret_cast<const f32x4*>(xb_ + (size_t)(t + 2) * XD + lgr * 8 + 4);
                }
            }
        }
        BAR();

        // ================= P2: s4 + s5 + z + s6 + s2(t+1) =================
        half8 a1b0 = mk8(A1W[wofs(2 * lgr, lcol)], A1W[wofs(2 * lgr + 1, lcol)]);
        half8 a1b1 = mk8(A1W[wofs(8 + 2 * lgr, lcol)], A1W[wofs(9 + 2 * lgr, lcol)]);
        half8 axb0 = mk8(AXW[wofs(2 * lgr, lcol)], AXW[wofs(2 * lgr + 1, lcol)]);
        half8 axb1 = mk8(AXW[wofs(8 + 2 * lgr, lcol)], AXW[wofs(9 + 2 * lgr, lcol)]);

        half4 enb[4];
#pragma unroll
        for (int o = 0; o < 4; ++o) {
            f32x4 e = MFMA32(we2f[o][1], a1b1, MFMA32(we2f[o][0], a1b0, BE2[o]));
            union { h2t p[2]; half4 h; } c;
            c.p[0] = pkrtz(fmaxf(e[0], 0.f), fmaxf(e[1], 0.f));
            c.p[1] = pkrtz(fmaxf(e[2], 0.f), fmaxf(e[3], 0.f));
            enb[o] = c.h;
        }
        f32x4 am = MFMA16(wemf[1], enb[1], MFMA16(wemf[0], enb[0], BM));
        f32x4 am2 = MFMA16(wemf[3], enb[3], MFMA16(wemf[2], enb[2], Z4()));
        f32x4 as_ = MFMA16(wesf[1], enb[1], MFMA16(wesf[0], enb[0], BS));
        f32x4 as2 = MFMA16(wesf[3], enb[3], MFMA16(wesf[2], enb[2], Z4()));
        f32x4 eC = fe;
        if (t + 1 < TT) fe = *reinterpret_cast<const f32x4*>(eb_ + (size_t)(t + 1) * ZD + lgr * 4);
        f32x4 zD;
#pragma unroll
        for (int q = 0; q < 4; ++q)
            zD[q] = eC[q] * softplus_f(as_[q] + as2[q]) + (am[q] + am2[q]);
        half4 zb = u2h4(packD(zD));
        {   // s6: phi_z o-tile ws
            f32x4 a = MFMA16(wzf, zb, BZ);
            if (t == TT - 1) {
#pragma unroll
                for (int q = 0; q < 4; ++q) pzlast[q] = fmaxf(a[q], 0.0f);
            }
            PZW[wofs(ws * 4 + lgr, lcol)] = packDr(a);
        }
        if (t + 1 < TT) {   // s2(t+1)
            f32x4 s = MFMA32(wx2f[1], axb1, MFMA32(wx2f[0], axb0, B2));
            PXW[(t + 1) & 1][wofs(ws * 4 + lgr, lcol)] = packDr(s);
        }
        BAR();

        // ================= P3: GRU gates + h update =================
        half8 pzb0 = mk8(PZW[wofs(2 * lgr, lcol)], PZW[wofs(2 * lgr + 1, lcol)]);
        half8 pzb1 = mk8(PZW[wofs(8 + 2 * lgr, lcol)], PZW[wofs(9 + 2 * lgr, lcol)]);
        f32x4 gi[3];
#pragma unroll
        for (int g = 0; g < 3; ++g) {
            f32x4 p = MFMA32(wihf[g][1], pxb1, MFMA32(wihf[g][0], pxb0, (g < 2) ? ga[g] : Z4()));
            f32x4 q = MFMA32(wihf[g][3], pzb1, MFMA32(wihf[g][2], pzb0, Z4()));
            gi[g] = p + q;
        }
#pragma unroll
        for (int q = 0; q < 4; ++q) {
            float rr = sigm(gi[0][q]);
            float uu = sigm(gi[1][q]);
            float nn = tanh_fast(gi[2][q] + rr * ga[2][q]);
            hD[q] = (1.0f - uu) * nn + uu * hD[q];
        }
        HW[wofs(ws * 4 + lgr, lcol)] = packD_rne(hD);
        BAR();
    }

    // ---------------- outputs ----------------
    float* po = out + BB + (size_t)(r0 + lcol) * 64;
    *reinterpret_cast<f32x4*>(po + o0w + lgr * 4) = pzlast;

    if (ws == 0) {
        // read pz back as x16 B-frags (word g = kt*4+lgr)
        half4 pzbL[4];
#pragma unroll
        for (int kt = 0; kt < 4; ++kt) pzbL[kt] = u2h4(PZW[wofs(kt * 4 + lgr, lcol)]);
        half4 wf1t[4][4], wf2t[2][4], wf3t[2];
#pragma unroll
        for (int o = 0; o < 4; ++o)
#pragma unroll
            for (int kt = 0; kt < 4; ++kt) wf1t[o][kt] = ldw(Wf1, 64, 64, 64, kt * 16, o * 16, lane);
#pragma unroll
        for (int o = 0; o < 2; ++o)
#pragma unroll
            for (int kt = 0; kt < 4; ++kt) wf2t[o][kt] = ldw(Wf2, 32, 64, 32, kt * 16, o * 16, lane);
        wf3t[0] = ldw(Wf3, 1, 32, 1, 0, 0, lane);
        wf3t[1] = ldw(Wf3, 1, 32, 1, 16, 0, lane);

        half4 o1b[4];
#pragma unroll
        for (int o = 0; o < 4; ++o) {
            f32x4 a = ldb4(bf1, o, lgr);
#pragma unroll
            for (int kt = 0; kt < 4; ++kt) a = MFMA16(wf1t[o][kt], pzbL[kt], a);
            union { h2t p[2]; half4 h; } c;
            c.p[0] = pkrtz(fmaxf(a[0], 0.f), fmaxf(a[1], 0.f));
            c.p[1] = pkrtz(fmaxf(a[2], 0.f), fmaxf(a[3], 0.f));
            o1b[o] = c.h;
        }
        half4 o2b[2];
#pragma unroll
        for (int o = 0; o < 2; ++o) {
            f32x4 a = ldb4(bf2, o, lgr);
#pragma unroll
            for (int kt = 0; kt < 4; ++kt) a = MFMA16(wf2t[o][kt], o1b[kt], a);
            union { h2t p[2]; half4 h; } c;
            c.p[0] = pkrtz(fmaxf(a[0], 0.f), fmaxf(a[1], 0.f));
            c.p[1] = pkrtz(fmaxf(a[2], 0.f), fmaxf(a[3], 0.f));
            o2b[o] = c.h;
        }
        float b3 = bf3[0];
        f32x4 p = (f32x4){b3, b3, b3, b3};
        p = MFMA16(wf3t[0], o2b[0], p);
        p = MFMA16(wf3t[1], o2b[1], p);
        if (lgr == 0) out[r0 + lcol] = p[0];
    }
}

extern "C" void kernel_launch(void* const* d_in, const int* in_sizes, int n_in,
                              void* d_out, int out_size, void* d_ws, size_t ws_size,
                              hipStream_t stream) {
    (void)in_sizes; (void)n_in; (void)d_ws; (void)ws_size; (void)out_size;
    const float* src = (const float*)d_in[0];
    const float* eps = (const float*)d_in[1];
    const float* Wx1 = (const float*)d_in[2];
    const float* bx1 = (const float*)d_in[3];
    const float* Wx2 = (const float*)d_in[4];
    const float* bx2 = (const float*)d_in[5];
    const float* Wz  = (const float*)d_in[6];
    const float* bz  = (const float*)d_in[7];
    const float* We1 = (const float*)d_in[8];
    const float* be1 = (const float*)d_in[9];
    const float* We2 = (const float*)d_in[10];
    const float* be2 = (const float*)d_in[11];
    const float* Wem = (const float*)d_in[12];
    const float* bem = (const float*)d_in[13];
    const float* Wes = (const float*)d_in[14];
    const float* bes = (const float*)d_in[15];
    const float* Wih = (const float*)d_in[16];
    const float* Whh = (const float*)d_in[17];
    const float* Wf1 = (const float*)d_in[18];
    const float* bf1 = (const float*)d_in[19];
    const float* Wf2 = (const float*)d_in[20];
    const float* bf2 = (const float*)d_in[21];
    const float* Wf3 = (const float*)d_in[22];
    const float* bf3 = (const float*)d_in[23];
    float* out = (float*)d_out;

    hipLaunchKernelGGL(vrnn_kernel, dim3(BB / 16), dim3(256), 0, stream,
                       src, eps, Wx1, bx1, Wx2, bx2, Wz, bz, We1, be1, We2, be2,
                       Wem, bem, Wes, bes, Wih, Whh, Wf1, bf1, Wf2, bf2, Wf3, bf3, out);
}

// Round 11
// 952.101 us; speedup vs baseline: 3.4861x; 1.4129x over previous
//
#include <hip/hip_runtime.h>

#define TT 512
#define BB 1024
#define XD 24
#define ZD 16

typedef __attribute__((ext_vector_type(4))) _Float16 half4;
typedef __attribute__((ext_vector_type(4))) float f32x4;
typedef unsigned long long u64;

__device__ __forceinline__ f32x4 MFMA16(half4 a, half4 b, f32x4 c) {
#if defined(__HIP_DEVICE_COMPILE__)
    return __builtin_amdgcn_mfma_f32_16x16x16f16(a, b, c, 0, 0, 0);
#else
    return c;   // host pass only needs to parse
#endif
}

__device__ __forceinline__ float rcpf(float x) {
#if defined(__HIP_DEVICE_COMPILE__)
    return __builtin_amdgcn_rcpf(x);
#else
    return 1.0f / x;
#endif
}

// Raw barrier: waits LDS ops only; global prefetch loads stay in flight.
#define BAR() asm volatile("s_waitcnt lgkmcnt(0)\n\ts_barrier" ::: "memory")

__device__ __forceinline__ f32x4 Z4() { return (f32x4){0.f, 0.f, 0.f, 0.f}; }

__device__ __forceinline__ float sigm(float x) { return rcpf(1.0f + __expf(-x)); }

__device__ __forceinline__ float tanh_fast(float x) {
    return 1.0f - 2.0f * rcpf(1.0f + __expf(2.0f * x));   // saturates via inf/rcp
}

__device__ __forceinline__ float softplus_f(float x) {
    return fmaxf(x, 0.0f) + __logf(1.0f + __expf(-fabsf(x)));
}

// A-fragment of W^T (16 out-feats x 16 k). Lane l holds W[k0+(l>>4)*4+j][o0+(l&15)],
// zero-padded outside Kreal/Nreal. W row-major [K][N].
__device__ __forceinline__ half4 ldw(const float* W, int N, int Kreal, int Nreal,
                                     int k0, int o0, int lane) {
    int col = o0 + (lane & 15);
    int kb = k0 + ((lane >> 4) << 2);
    half4 r;
#pragma unroll
    for (int j = 0; j < 4; ++j) {
        int k = kb + j;
        float v = (k < Kreal && col < Nreal) ? W[(size_t)k * N + col] : 0.0f;
        r[j] = (_Float16)v;
    }
    return r;
}

__device__ __forceinline__ half4 cvt_relu(f32x4 a) {
    half4 r;
#pragma unroll
    for (int q = 0; q < 4; ++q) r[q] = (_Float16)fmaxf(a[q], 0.0f);
    return r;
}

__device__ __forceinline__ half4 cvt4(f32x4 a) {
    half4 r;
#pragma unroll
    for (int q = 0; q < 4; ++q) r[q] = (_Float16)a[q];
    return r;
}

__device__ __forceinline__ f32x4 ldb4(const float* b, int o, int lgr) {
    return *reinterpret_cast<const f32x4*>(b + o * 16 + lgr * 4);
}

__device__ __forceinline__ u64 h2u(half4 h) {
    union { half4 h; u64 u; } c; c.h = h; return c.u;
}
__device__ __forceinline__ half4 u2h(u64 u) {
    union { half4 h; u64 u; } c; c.u = u; return c.h;
}

__global__ __launch_bounds__(256, 1) void vrnn_kernel(
    const float* __restrict__ src, const float* __restrict__ eps,
    const float* __restrict__ Wx1, const float* __restrict__ bx1,
    const float* __restrict__ Wx2, const float* __restrict__ bx2,
    const float* __restrict__ Wz,  const float* __restrict__ bz,
    const float* __restrict__ We1, const float* __restrict__ be1,
    const float* __restrict__ We2, const float* __restrict__ be2,
    const float* __restrict__ Wem, const float* __restrict__ bem,
    const float* __restrict__ Wes, const float* __restrict__ bes,
    const float* __restrict__ Wih, const float* __restrict__ Whh,
    const float* __restrict__ Wf1, const float* __restrict__ bf1,
    const float* __restrict__ Wf2, const float* __restrict__ bf2,
    const float* __restrict__ Wf3, const float* __restrict__ bf3,
    float* __restrict__ out)
{
    // Activation exchange buffers, B-fragment form (8B/lane/frag)
    __shared__ u64 AXB[4 * 64];     // ax(t+1)
    __shared__ u64 A1B[4 * 64];     // a1(t)
    __shared__ u64 HB[4 * 64];      // h
    __shared__ u64 PXB[2][4 * 64];  // phi_x, double-buffered

    const int tid = threadIdx.x;
    const int ws = tid >> 6;       // wave id = o-tile slice
    const int lane = tid & 63;
    const int lcol = lane & 15;    // batch column
    const int lgr = lane >> 4;
    const int r0 = blockIdx.x * 16;
    const int o0w = ws * 16;

    // ---------------- weights (registers, per-wave slices) ----------------
    half4 wx1f[2], wx2f[4], we1f[8], we2f[4][4], wemf[4], wesf[4], wzf4[4];
    wx1f[0] = ldw(Wx1, 64, 24, 64, 0, o0w, lane);
    wx1f[1] = ldw(Wx1, 64, 24, 64, 16, o0w, lane);
#pragma unroll
    for (int kt = 0; kt < 4; ++kt) wx2f[kt] = ldw(Wx2, 64, 64, 64, kt * 16, o0w, lane);
#pragma unroll
    for (int kt = 0; kt < 8; ++kt) we1f[kt] = ldw(We1, 64, 128, 64, kt * 16, o0w, lane);
#pragma unroll
    for (int o = 0; o < 4; ++o)
#pragma unroll
        for (int kt = 0; kt < 4; ++kt) we2f[o][kt] = ldw(We2, 64, 64, 64, kt * 16, o * 16, lane);
#pragma unroll
    for (int kt = 0; kt < 4; ++kt) {
        wemf[kt] = ldw(Wem, 16, 64, 16, kt * 16, 0, lane);
        wesf[kt] = ldw(Wes, 16, 64, 16, kt * 16, 0, lane);
    }
#pragma unroll
    for (int o = 0; o < 4; ++o) wzf4[o] = ldw(Wz, 64, 16, 64, 0, o * 16, lane);
    half4 wihf[3][8], whhf[3][4];
#pragma unroll
    for (int g = 0; g < 3; ++g) {
#pragma unroll
        for (int kt = 0; kt < 8; ++kt) wihf[g][kt] = ldw(Wih, 192, 128, 192, kt * 16, g * 64 + o0w, lane);
#pragma unroll
        for (int kt = 0; kt < 4; ++kt) whhf[g][kt] = ldw(Whh, 192, 64, 192, kt * 16, g * 64 + o0w, lane);
    }
    const f32x4 B1 = ldb4(bx1, ws, lgr), B2 = ldb4(bx2, ws, lgr);
    const f32x4 BE1 = ldb4(be1, ws, lgr);
    f32x4 BE2[4], BZf[4];
#pragma unroll
    for (int o = 0; o < 4; ++o) {
        BE2[o] = ldb4(be2, o, lgr);
        BZf[o] = ldb4(bz, o, lgr);
    }
    const f32x4 BM = ldb4(bem, 0, lgr), BS = ldb4(bes, 0, lgr);

    const float* xb_ = src + (size_t)(r0 + lcol) * TT * XD;
    const float* eb_ = eps + (size_t)(r0 + lcol) * TT * ZD;
    float* po = out + BB + (size_t)(r0 + lcol) * 64;

    // ---------------- prologue: phi_x(0) -> PXB[0]; h = 0 ----------------
    f32x4 fx0 = *reinterpret_cast<const f32x4*>(xb_ + lgr * 4);
    f32x4 fx1 = Z4();
    if (lgr < 2) fx1 = *reinterpret_cast<const f32x4*>(xb_ + 16 + lgr * 4);
    {
        half4 x0 = cvt4(fx0), x1 = cvt4(fx1);
        f32x4 a = MFMA16(wx1f[1], x1, MFMA16(wx1f[0], x0, B1));
        AXB[ws * 64 + lane] = h2u(cvt_relu(a));
    }
    HB[ws * 64 + lane] = 0ull;
    f32x4 hD = Z4();
    BAR();
    {
        half4 axb[4];
#pragma unroll
        for (int kt = 0; kt < 4; ++kt) axb[kt] = u2h(AXB[kt * 64 + lane]);
        f32x4 a = B2;
#pragma unroll
        for (int kt = 0; kt < 4; ++kt) a = MFMA16(wx2f[kt], axb[kt], a);
        PXB[0][ws * 64 + lane] = h2u(cvt_relu(a));
    }
    // prefetch x(1), eps(0) — stay in flight across raw barriers
    fx0 = *reinterpret_cast<const f32x4*>(xb_ + XD + lgr * 4);
    fx1 = Z4();
    if (lgr < 2) fx1 = *reinterpret_cast<const f32x4*>(xb_ + XD + 16 + lgr * 4);
    f32x4 fe = *reinterpret_cast<const f32x4*>(eb_ + lgr * 4);
    BAR();

    half4 pxb[4], pzb[4];

#pragma unroll 1
    for (int t = 0; t < TT; ++t) {
        // ================= P1: s3 + gh + s1(t+1) =================
        half4 hb[4];
#pragma unroll
        for (int kt = 0; kt < 4; ++kt) hb[kt] = u2h(HB[kt * 64 + lane]);
#pragma unroll
        for (int kt = 0; kt < 4; ++kt) pxb[kt] = u2h(PXB[t & 1][kt * 64 + lane]);

        {   // s3: a1 o-tile ws
            f32x4 a = BE1;
#pragma unroll
            for (int kt = 0; kt < 4; ++kt) a = MFMA16(we1f[kt], pxb[kt], a);
            f32x4 b = Z4();
#pragma unroll
            for (int kt = 0; kt < 4; ++kt) b = MFMA16(we1f[4 + kt], hb[kt], b);
            A1B[ws * 64 + lane] = h2u(cvt_relu(a + b));
        }
        f32x4 ga[3];
#pragma unroll
        for (int g = 0; g < 3; ++g) {   // gh for r,u,n (col-slice ws)
            f32x4 a = MFMA16(whhf[g][1], hb[1], MFMA16(whhf[g][0], hb[0], Z4()));
            f32x4 b = MFMA16(whhf[g][3], hb[3], MFMA16(whhf[g][2], hb[2], Z4()));
            ga[g] = a + b;
        }
        if (t + 1 < TT) {   // s1(t+1)
            half4 x0 = cvt4(fx0), x1 = cvt4(fx1);
            f32x4 s = MFMA16(wx1f[1], x1, MFMA16(wx1f[0], x0, B1));
            AXB[ws * 64 + lane] = h2u(cvt_relu(s));
            if (t + 2 < TT) {
                fx0 = *reinterpret_cast<const f32x4*>(xb_ + (size_t)(t + 2) * XD + lgr * 4);
                fx1 = Z4();
                if (lgr < 2) fx1 = *reinterpret_cast<const f32x4*>(xb_ + (size_t)(t + 2) * XD + 16 + lgr * 4);
            }
        }
        BAR();

        // ============ P2 (fused): s4 + s5 + z + s6-full + GRU + h update + s2(t+1) ======
        half4 a1b[4];
#pragma unroll
        for (int kt = 0; kt < 4; ++kt) a1b[kt] = u2h(A1B[kt * 64 + lane]);
        half4 enb[4];
#pragma unroll
        for (int o = 0; o < 4; ++o) {
            f32x4 a = MFMA16(we2f[o][1], a1b[1], MFMA16(we2f[o][0], a1b[0], BE2[o]));
            f32x4 b = MFMA16(we2f[o][3], a1b[3], MFMA16(we2f[o][2], a1b[2], Z4()));
            enb[o] = cvt_relu(a + b);
        }
        f32x4 am = MFMA16(wemf[1], enb[1], MFMA16(wemf[0], enb[0], BM));
        f32x4 am2 = MFMA16(wemf[3], enb[3], MFMA16(wemf[2], enb[2], Z4()));
        f32x4 as_ = MFMA16(wesf[1], enb[1], MFMA16(wesf[0], enb[0], BS));
        f32x4 as2 = MFMA16(wesf[3], enb[3], MFMA16(wesf[2], enb[2], Z4()));
        f32x4 eC = fe;
        if (t + 1 < TT) fe = *reinterpret_cast<const f32x4*>(eb_ + (size_t)(t + 1) * ZD + lgr * 4);
        f32x4 zD;
#pragma unroll
        for (int q = 0; q < 4; ++q)
            zD[q] = eC[q] * softplus_f(as_[q] + as2[q]) + (am[q] + am2[q]);
        half4 zb = cvt4(zD);
        // s6-full: phi_z all 4 o-tiles in-register (D≡B feeds gi directly)
#pragma unroll
        for (int o = 0; o < 4; ++o) {
            f32x4 a = MFMA16(wzf4[o], zb, BZf[o]);
            if (t == TT - 1 && ws == 0) {
                f32x4 pr;
#pragma unroll
                for (int q = 0; q < 4; ++q) pr[q] = fmaxf(a[q], 0.0f);
                *reinterpret_cast<f32x4*>(po + o * 16 + lgr * 4) = pr;
            }
            pzb[o] = cvt_relu(a);
        }
        // GRU gates (col-slice ws local)
        f32x4 gi[3];
#pragma unroll
        for (int g = 0; g < 3; ++g) {
            f32x4 p = (g < 2) ? ga[g] : Z4();
#pragma unroll
            for (int kt = 0; kt < 4; ++kt) p = MFMA16(wihf[g][kt], pxb[kt], p);
            f32x4 q = Z4();
#pragma unroll
            for (int kt = 0; kt < 4; ++kt) q = MFMA16(wihf[g][4 + kt], pzb[kt], q);
            gi[g] = p + q;
        }
#pragma unroll
        for (int q = 0; q < 4; ++q) {
            float rr = sigm(gi[0][q]);
            float uu = sigm(gi[1][q]);
            float nn = tanh_fast(gi[2][q] + rr * ga[2][q]);
            hD[q] = (1.0f - uu) * nn + uu * hD[q];
        }
        HB[ws * 64 + lane] = h2u(cvt4(hD));
        if (t + 1 < TT) {   // s2(t+1)
            half4 axb[4];
#pragma unroll
            for (int kt = 0; kt < 4; ++kt) axb[kt] = u2h(AXB[kt * 64 + lane]);
            f32x4 s = B2;
#pragma unroll
            for (int kt = 0; kt < 4; ++kt) s = MFMA16(wx2f[kt], axb[kt], s);
            PXB[(t + 1) & 1][ws * 64 + lane] = h2u(cvt_relu(s));
        }
        BAR();
    }

    // ---------------- regressor head (wave 0; pzb held in registers) ----------------
    if (ws == 0) {
        half4 wf1t[4][4], wf2t[2][4], wf3t[2];
#pragma unroll
        for (int o = 0; o < 4; ++o)
#pragma unroll
            for (int kt = 0; kt < 4; ++kt) wf1t[o][kt] = ldw(Wf1, 64, 64, 64, kt * 16, o * 16, lane);
#pragma unroll
        for (int o = 0; o < 2; ++o)
#pragma unroll
            for (int kt = 0; kt < 4; ++kt) wf2t[o][kt] = ldw(Wf2, 32, 64, 32, kt * 16, o * 16, lane);
        wf3t[0] = ldw(Wf3, 1, 32, 1, 0, 0, lane);
        wf3t[1] = ldw(Wf3, 1, 32, 1, 16, 0, lane);

        half4 o1b[4];
#pragma unroll
        for (int o = 0; o < 4; ++o) {
            f32x4 a = ldb4(bf1, o, lgr);
#pragma unroll
            for (int kt = 0; kt < 4; ++kt) a = MFMA16(wf1t[o][kt], pzb[kt], a);
            o1b[o] = cvt_relu(a);
        }
        half4 o2b[2];
#pragma unroll
        for (int o = 0; o < 2; ++o) {
            f32x4 a = ldb4(bf2, o, lgr);
#pragma unroll
            for (int kt = 0; kt < 4; ++kt) a = MFMA16(wf2t[o][kt], o1b[kt], a);
            o2b[o] = cvt_relu(a);
        }
        float b3 = bf3[0];
        f32x4 p = (f32x4){b3, b3, b3, b3};
        p = MFMA16(wf3t[0], o2b[0], p);
        p = MFMA16(wf3t[1], o2b[1], p);
        if (lgr == 0) out[r0 + lcol] = p[0];
    }
}

extern "C" void kernel_launch(void* const* d_in, const int* in_sizes, int n_in,
                              void* d_out, int out_size, void* d_ws, size_t ws_size,
                              hipStream_t stream) {
    (void)in_sizes; (void)n_in; (void)d_ws; (void)ws_size; (void)out_size;
    const float* src = (const float*)d_in[0];
    const float* eps = (const float*)d_in[1];
    const float* Wx1 = (const float*)d_in[2];
    const float* bx1 = (const float*)d_in[3];
    const float* Wx2 = (const float*)d_in[4];
    const float* bx2 = (const float*)d_in[5];
    const float* Wz  = (const float*)d_in[6];
    const float* bz  = (const float*)d_in[7];
    const float* We1 = (const float*)d_in[8];
    const float* be1 = (const float*)d_in[9];
    const float* We2 = (const float*)d_in[10];
    const float* be2 = (const float*)d_in[11];
    const float* Wem = (const float*)d_in[12];
    const float* bem = (const float*)d_in[13];
    const float* Wes = (const float*)d_in[14];
    const float* bes = (const float*)d_in[15];
    const float* Wih = (const float*)d_in[16];
    const float* Whh = (const float*)d_in[17];
    const float* Wf1 = (const float*)d_in[18];
    const float* bf1 = (const float*)d_in[19];
    const float* Wf2 = (const float*)d_in[20];
    const float* bf2 = (const float*)d_in[21];
    const float* Wf3 = (const float*)d_in[22];
    const float* bf3 = (const float*)d_in[23];
    float* out = (float*)d_out;

    hipLaunchKernelGGL(vrnn_kernel, dim3(BB / 16), dim3(256), 0, stream,
                       src, eps, Wx1, bx1, Wx2, bx2, Wz, bz, We1, be1, We2, be2,
                       Wem, bem, Wes, bes, Wih, Whh, Wf1, bf1, Wf2, bf2, Wf3, bf3, out);
}